// Round 6
// baseline (370.503 us; speedup 1.0000x reference)
//
#include <hip/hip_runtime.h>
#include <stdint.h>

typedef __attribute__((ext_vector_type(8))) short short8;
typedef __attribute__((ext_vector_type(4))) float f32x4;
typedef unsigned short u16;

__device__ __forceinline__ u16 f2bf(float f) {
  union { float f; uint32_t u; } v; v.f = f;
  return (u16)((v.u + 0x7FFFu + ((v.u >> 16) & 1u)) >> 16);
}
__device__ __forceinline__ float bf2f(u16 u) {
  union { uint32_t u; float f; } v; v.u = (uint32_t)u << 16; return v.f;
}

__device__ __forceinline__ void gl_lds16(const void* g, void* l) {
  __builtin_amdgcn_global_load_lds(
      (const __attribute__((address_space(1))) void*)g,
      (__attribute__((address_space(3))) void*)l, 16, 0, 0);
}

// ---------------- generic GEMM (m97 structure, 128x128) ----------------
__global__ __launch_bounds__(256) void gemm_bt(
    const u16* __restrict__ A, const u16* __restrict__ B,
    float* __restrict__ Cf, u16* __restrict__ Cb,
    const float* __restrict__ bias1,
    int M, int N, int K)
{
  __shared__ __align__(16) u16 As[128 * 32];
  __shared__ __align__(16) u16 Bs[128 * 32];
  const int t = threadIdx.x;
  const int lane = t & 63;
  const int w = t >> 6;
  const int wr = w >> 1, wc = w & 1;
  const int m0 = blockIdx.y * 128, n0 = blockIdx.x * 128;
  const int lr = lane & 15;
  const int lk = (lane >> 4) * 8;
  const int srow = t >> 2;
  const int scol = (t & 3) * 8;

  const u16* gA = A + (size_t)(m0 + srow) * K + scol;
  const u16* gB = B + (size_t)(n0 + srow) * K + scol;

  f32x4 acc[4][4] = {};

  for (int k0 = 0; k0 < K; k0 += 32) {
    gl_lds16(gA,                  As + t * 8);
    gl_lds16(gA + (size_t)64 * K, As + 2048 + t * 8);
    gl_lds16(gB,                  Bs + t * 8);
    gl_lds16(gB + (size_t)64 * K, Bs + 2048 + t * 8);
    gA += 32; gB += 32;
    __syncthreads();

    short8 a[4], b[4];
#pragma unroll
    for (int m = 0; m < 4; ++m)
      a[m] = *(const short8*)(As + (wr * 64 + m * 16 + lr) * 32 + lk);
#pragma unroll
    for (int n = 0; n < 4; ++n)
      b[n] = *(const short8*)(Bs + (wc * 64 + n * 16 + lr) * 32 + lk);
#pragma unroll
    for (int m = 0; m < 4; ++m)
#pragma unroll
      for (int n = 0; n < 4; ++n)
        acc[m][n] = __builtin_amdgcn_mfma_f32_16x16x32_bf16(a[m], b[n], acc[m][n], 0, 0, 0);
    __syncthreads();
  }

#pragma unroll
  for (int n = 0; n < 4; ++n) {
    int col = n0 + wc * 64 + n * 16 + lr;
    float bsum = bias1 ? bias1[col] : 0.f;
#pragma unroll
    for (int m = 0; m < 4; ++m) {
#pragma unroll
      for (int r = 0; r < 4; ++r) {
        int row = m0 + wr * 64 + m * 16 + (lane >> 4) * 4 + r;
        float vv = acc[m][n][r] + bsum;
        if (Cf) Cf[(size_t)row * N + col] = vv;
        if (Cb) Cb[(size_t)row * N + col] = f2bf(vv);
      }
    }
  }
}

// ---------------- prep: all f32->bf16 packs + Wq/Wk transposes ----------------
__global__ __launch_bounds__(256) void prep_k(
    const float* __restrict__ pose, const float* __restrict__ h,
    const float* __restrict__ W_ih, const float* __restrict__ W_hh,
    const float* __restrict__ query, const float* __restrict__ Wv,
    const float* __restrict__ Wq, const float* __restrict__ Wk,
    u16* __restrict__ xcat, u16* __restrict__ wcat,
    u16* __restrict__ qry, u16* __restrict__ wvb,
    u16* __restrict__ wqtb, u16* __restrict__ wktb)
{
  __shared__ u16 tile[64][65];
  int blk = blockIdx.x;
  int t = threadIdx.x;
  if (blk >= 15360) {  // transpose-convert: dst[n*1024+a] = bf16(src[a*1024+n])
    const float* src; u16* dst; int tblk;
    if (blk < 15616) { src = Wq; dst = wqtb; tblk = blk - 15360; }
    else             { src = Wk; dst = wktb; tblk = blk - 15616; }
    int tr = (tblk >> 4) * 64, tc = (tblk & 15) * 64;
    int tx = t & 63;
    int ty = (t >> 6) * 16;
#pragma unroll
    for (int i = 0; i < 16; ++i)
      tile[ty + i][tx] = f2bf(src[(size_t)(tr + ty + i) * 1024 + tc + tx]);
    __syncthreads();
#pragma unroll
    for (int i = 0; i < 16; ++i)
      dst[(size_t)(tc + ty + i) * 1024 + tr + tx] = tile[tx][ty + i];
    return;
  }
  const float* src; u16* dst; int ostride, ooff, base;
  if (blk < 2048)       { src = pose;  dst = xcat; ostride = 2048; ooff = 0;    base = 0; }
  else if (blk < 4096)  { src = h;     dst = xcat; ostride = 2048; ooff = 1024; base = 2048; }
  else if (blk < 8192)  { src = W_ih;  dst = wcat; ostride = 2048; ooff = 0;    base = 4096; }
  else if (blk < 12288) { src = W_hh;  dst = wcat; ostride = 2048; ooff = 1024; base = 8192; }
  else if (blk < 14336) { src = query; dst = qry;  ostride = 1024; ooff = 0;    base = 12288; }
  else                  { src = Wv;    dst = wvb;  ostride = 1024; ooff = 0;    base = 14336; }
  int r = blk - base;
  int cc = t * 4;
  float4 v = *(const float4*)(src + (size_t)r * 1024 + cc);
  ushort4 o; o.x = f2bf(v.x); o.y = f2bf(v.y); o.z = f2bf(v.z); o.w = f2bf(v.w);
  *(ushort4*)(dst + (size_t)r * ostride + ooff + cc) = o;
}

// qkb[n] += partial of bq @ Wk (qkb pre-zeroed via memset)
__global__ __launch_bounds__(256) void bqwk_k(
    const float* __restrict__ bq, const float* __restrict__ Wk,
    float* __restrict__ qkb)
{
  int n = blockIdx.x * 256 + threadIdx.x;
  int j0 = blockIdx.y * 64;
  float s = 0.f;
#pragma unroll 8
  for (int j = j0; j < j0 + 64; ++j) s += bq[j] * Wk[(size_t)j * 1024 + n];
  atomicAdd(&qkb[n], s);
}

// ---------------- mega: gates GEMM (128x64 tiles) + attention partial -------
// 1536 blocks, 4/CU, no spills (both branches <= ~110 VGPR).
// blk%3 in {0,1} -> gemm (1024 tiles), blk%3==2 -> attn (512 blocks).
__global__ __launch_bounds__(256, 4) void mega_k(
    const u16* __restrict__ Xcat, const u16* __restrict__ Wcat,
    u16* __restrict__ gates,
    const float* __restrict__ b_ih, const float* __restrict__ b_hh,
    const float* __restrict__ Qk, const float* __restrict__ mem,
    float* __restrict__ attst)
{
  __shared__ __align__(16) u16 As[128 * 32];
  __shared__ __align__(16) u16 Bs[64 * 32];
  const int blk = blockIdx.x;
  const int t = threadIdx.x;
  const int lane = t & 63;

  if (blk % 3 != 2) {
    // ---- gates GEMM tile 128x64: M=2048 N=4096 K=2048, bf16 out ----
    const int gid = (blk / 3) * 2 + (blk % 3);      // 0..1023
    const int m0 = (gid >> 6) * 128, n0 = (gid & 63) * 64;
    const int w = t >> 6;                            // wave: rows w*32..w*32+31
    const int lr = lane & 15;
    const int lk = (lane >> 4) * 8;
    const int srow = t >> 2;
    const int scol = (t & 3) * 8;

    const u16* gA = Xcat + (size_t)(m0 + srow) * 2048 + scol;
    const u16* gB = Wcat + (size_t)(n0 + srow) * 2048 + scol;

    f32x4 acc[2][4] = {};
    for (int k0 = 0; k0 < 2048; k0 += 32) {
      gl_lds16(gA,                     As + t * 8);
      gl_lds16(gA + (size_t)64 * 2048, As + 2048 + t * 8);
      gl_lds16(gB,                     Bs + t * 8);
      gA += 32; gB += 32;
      __syncthreads();
      short8 a[2], b[4];
#pragma unroll
      for (int m = 0; m < 2; ++m)
        a[m] = *(const short8*)(As + (w * 32 + m * 16 + lr) * 32 + lk);
#pragma unroll
      for (int n = 0; n < 4; ++n)
        b[n] = *(const short8*)(Bs + (n * 16 + lr) * 32 + lk);
#pragma unroll
      for (int m = 0; m < 2; ++m)
#pragma unroll
        for (int n = 0; n < 4; ++n)
          acc[m][n] = __builtin_amdgcn_mfma_f32_16x16x32_bf16(a[m], b[n], acc[m][n], 0, 0, 0);
      __syncthreads();
    }
#pragma unroll
    for (int n = 0; n < 4; ++n) {
      int col = n0 + n * 16 + lr;
      float bsum = b_ih[col] + b_hh[col];
#pragma unroll
      for (int m = 0; m < 2; ++m)
#pragma unroll
        for (int r = 0; r < 4; ++r) {
          int row = m0 + w * 32 + m * 16 + (lane >> 4) * 4 + r;
          gates[(size_t)row * 4096 + col] = f2bf(acc[m][n][r] + bsum);
        }
    }
  } else {
    // ---- attention partial: 1 batch per wave, quad-row ----
    const int b = (blk / 3) * 4 + (t >> 6);          // 0..2047
    const float* q = Qk + (size_t)b * 1024;
    f32x4 qv[4];
#pragma unroll
    for (int i = 0; i < 4; ++i)
      qv[i] = *(const f32x4*)(q + (i * 64 + lane) * 4);
    const float* mb = mem + (size_t)b * 65536;

    float m_run = -3e38f, l = 0.f;
    f32x4 cx[4] = {};

    // 15 quads: rows 1..60
    for (int qd = 0; qd < 15; ++qd) {
      const float* r0 = mb + (size_t)(1 + qd * 4) * 1024;
      f32x4 rv[4][4];
      float s[4] = {0.f, 0.f, 0.f, 0.f};
#pragma unroll
      for (int rr = 0; rr < 4; ++rr)
#pragma unroll
        for (int i = 0; i < 4; ++i) {
          rv[rr][i] = *(const f32x4*)(r0 + rr * 1024 + (i * 64 + lane) * 4);
          s[rr] += rv[rr][i][0] * qv[i][0] + rv[rr][i][1] * qv[i][1] +
                   rv[rr][i][2] * qv[i][2] + rv[rr][i][3] * qv[i][3];
        }
#pragma unroll
      for (int rr = 0; rr < 4; ++rr) {
#pragma unroll
        for (int off = 32; off; off >>= 1) s[rr] += __shfl_xor(s[rr], off);
        s[rr] *= 0.03125f;
      }
#pragma unroll
      for (int rr = 0; rr < 4; ++rr) {
        if (s[rr] <= m_run + 8.f) {      // defer-max: common path
          float e = __expf(s[rr] - m_run);
          l += e;
#pragma unroll
          for (int i = 0; i < 4; ++i) cx[i] += rv[rr][i] * e;
        } else {
          float sc = __expf(m_run - s[rr]);
          m_run = s[rr];
          l = l * sc + 1.f;
#pragma unroll
          for (int i = 0; i < 4; ++i) cx[i] = cx[i] * sc + rv[rr][i];
        }
      }
    }
    // rows 61..63 singles
    for (int r = 61; r <= 63; ++r) {
      const float* row = mb + (size_t)r * 1024;
      f32x4 rv[4];
      float s = 0.f;
#pragma unroll
      for (int i = 0; i < 4; ++i) {
        rv[i] = *(const f32x4*)(row + (i * 64 + lane) * 4);
        s += rv[i][0] * qv[i][0] + rv[i][1] * qv[i][1] +
             rv[i][2] * qv[i][2] + rv[i][3] * qv[i][3];
      }
#pragma unroll
      for (int off = 32; off; off >>= 1) s += __shfl_xor(s, off);
      s *= 0.03125f;
      if (s <= m_run + 8.f) {
        float e = __expf(s - m_run);
        l += e;
#pragma unroll
        for (int i = 0; i < 4; ++i) cx[i] += rv[i] * e;
      } else {
        float sc = __expf(m_run - s);
        m_run = s;
        l = l * sc + 1.f;
#pragma unroll
        for (int i = 0; i < 4; ++i) cx[i] = cx[i] * sc + rv[i];
      }
    }
    // store state
    float* st = attst + (size_t)b * 1032;
#pragma unroll
    for (int i = 0; i < 4; ++i)
      *(f32x4*)(st + (i * 64 + lane) * 4) = cx[i];
    if (lane == 0) { st[1024] = m_run; st[1025] = l; }
  }
}

// ---------------- fused LSTM elementwise + attention finish ----------------
__global__ __launch_bounds__(256) void lstmfin_k(
    const u16* __restrict__ gates, const float* __restrict__ c,
    const float* __restrict__ Qk, const float* __restrict__ attst,
    float* __restrict__ out_h, float* __restrict__ out_c,
    u16* __restrict__ ctxb)
{
  const int b = blockIdx.x;
  const int t = threadIdx.x;
  const int lane = t & 63, wv_id = t >> 6;
  const int p = t * 4;
  const u16* g = gates + (size_t)b * 4096;
  ushort4 igu = *(const ushort4*)(g + p);
  ushort4 fgu = *(const ushort4*)(g + 1024 + p);
  ushort4 ggu = *(const ushort4*)(g + 2048 + p);
  ushort4 ogu = *(const ushort4*)(g + 3072 + p);
  float4 cv = *(const float4*)(c + (size_t)b * 1024 + p);

  float hn[4], cn[4];
  {
    float igs[4] = {bf2f(igu.x), bf2f(igu.y), bf2f(igu.z), bf2f(igu.w)};
    float fgs[4] = {bf2f(fgu.x), bf2f(fgu.y), bf2f(fgu.z), bf2f(fgu.w)};
    float ggs[4] = {bf2f(ggu.x), bf2f(ggu.y), bf2f(ggu.z), bf2f(ggu.w)};
    float ogs[4] = {bf2f(ogu.x), bf2f(ogu.y), bf2f(ogu.z), bf2f(ogu.w)};
    float cvs[4] = {cv.x, cv.y, cv.z, cv.w};
#pragma unroll
    for (int j = 0; j < 4; ++j) {
      float si = 1.f / (1.f + __expf(-igs[j]));
      float sf = 1.f / (1.f + __expf(-fgs[j]));
      float so = 1.f / (1.f + __expf(-ogs[j]));
      float tg = 2.f / (1.f + __expf(-2.f * ggs[j])) - 1.f;
      cn[j] = sf * cvs[j] + si * tg;
      float tc2 = 2.f / (1.f + __expf(-2.f * cn[j])) - 1.f;
      hn[j] = so * tc2;
    }
  }
  *(float4*)(out_c + (size_t)b * 1024 + p) = make_float4(cn[0], cn[1], cn[2], cn[3]);
  *(float4*)(out_h + (size_t)b * 1024 + p) = make_float4(hn[0], hn[1], hn[2], hn[3]);

  // s_last = dot(Qk[b], h_new[b]) / 32  (block reduction)
  float4 qv = *(const float4*)(Qk + (size_t)b * 1024 + p);
  float part = qv.x * hn[0] + qv.y * hn[1] + qv.z * hn[2] + qv.w * hn[3];
#pragma unroll
  for (int off = 32; off; off >>= 1) part += __shfl_xor(part, off);
  __shared__ float red[4];
  if (lane == 0) red[wv_id] = part;
  __syncthreads();
  float s_last = (red[0] + red[1] + red[2] + red[3]) * 0.03125f;

  const float* st = attst + (size_t)b * 1032;
  float m_run = st[1024], l = st[1025];
  float4 cx = *(const float4*)(st + p);
  if (s_last <= m_run + 8.f) {
    float e = __expf(s_last - m_run);
    l += e;
    cx.x += e * hn[0]; cx.y += e * hn[1]; cx.z += e * hn[2]; cx.w += e * hn[3];
  } else {
    float sc = __expf(m_run - s_last);
    l = l * sc + 1.f;
    cx.x = cx.x * sc + hn[0]; cx.y = cx.y * sc + hn[1];
    cx.z = cx.z * sc + hn[2]; cx.w = cx.w * sc + hn[3];
  }
  float inv = 1.f / l;
  ushort4 o;
  o.x = f2bf(cx.x * inv); o.y = f2bf(cx.y * inv);
  o.z = f2bf(cx.z * inv); o.w = f2bf(cx.w * inv);
  *(ushort4*)(ctxb + (size_t)b * 1024 + p) = o;
}

extern "C" void kernel_launch(void* const* d_in, const int* in_sizes, int n_in,
                              void* d_out, int out_size, void* d_ws, size_t ws_size,
                              hipStream_t stream) {
  const int Bb = 2048, Hh = 1024;
  const float* pose  = (const float*)d_in[0];
  const float* query = (const float*)d_in[1];
  const float* h     = (const float*)d_in[2];
  const float* c     = (const float*)d_in[3];
  const float* mem   = (const float*)d_in[4];
  const float* W_ih  = (const float*)d_in[5];
  const float* W_hh  = (const float*)d_in[6];
  const float* b_ih  = (const float*)d_in[7];
  const float* b_hh  = (const float*)d_in[8];
  const float* Wq    = (const float*)d_in[9];
  const float* bq    = (const float*)d_in[10];
  const float* Wk    = (const float*)d_in[11];
  // d_in[12] = bk: m-independent score shift, cancels in softmax
  const float* Wv    = (const float*)d_in[13];
  const float* bv    = (const float*)d_in[14];

  float* out_att = (float*)d_out;
  float* out_h   = out_att + (size_t)Bb * Hh;
  float* out_c   = out_h + (size_t)Bb * Hh;

  char* wp = (char*)d_ws;
  auto alloc = [&](size_t bytes) {
    char* p = wp; wp += (bytes + 255) & ~(size_t)255; return p;
  };
  u16*   Xcat  = (u16*)alloc((size_t)2048 * 2048 * 2);   // 8 MB
  u16*   Wcat  = (u16*)alloc((size_t)4096 * 2048 * 2);   // 16 MB
  // next 4 contiguous, all dead before mega -> attst aliases them
  u16*   Qryb  = (u16*)alloc((size_t)2048 * 1024 * 2);   // 4 MB
  u16*   WqTb  = (u16*)alloc((size_t)1024 * 1024 * 2);   // 2 MB
  u16*   WkTb  = (u16*)alloc((size_t)1024 * 1024 * 2);   // 2 MB
  u16*   Gb    = (u16*)alloc((size_t)1024 * 1024 * 2);   // 2 MB
  u16*   Wvb   = (u16*)alloc((size_t)1024 * 1024 * 2);   // 2 MB (live through final)
  u16*   gates = (u16*)alloc((size_t)2048 * 4096 * 2);   // 16 MB (bf16)
  float* qkb   = (float*)alloc((size_t)1024 * 4);
  float* Qk    = (float*)alloc((size_t)2048 * 1024 * 4); // 8 MB
  u16*   ctxb  = (u16*)alloc((size_t)2048 * 1024 * 2);   // 4 MB
  float* attst = (float*)Qryb;   // [2048][1032] f32 = 8.45 MB < 10 MB alias pool

  // 1. all conversions in one kernel
  prep_k<<<15872, 256, 0, stream>>>(pose, h, W_ih, W_hh, query, Wv, Wq, Wk,
                                    Xcat, Wcat, Qryb, Wvb, WqTb, WkTb);

  // 2. qkb = bq @ Wk (tiny)
  hipMemsetAsync(qkb, 0, 1024 * sizeof(float), stream);
  bqwk_k<<<dim3(4, 16), 256, 0, stream>>>(bq, Wk, qkb);

  // 3. G[n,j] = sum_a Wk[a,n]*Wq[a,j]  (query @ G^T == (query@Wq^T)@Wk)
  gemm_bt<<<dim3(8, 8), 256, 0, stream>>>(
      WkTb, WqTb, nullptr, Gb, nullptr, 1024, 1024, 1024);

  // 4. Qk = query @ G^T + bq@Wk
  gemm_bt<<<dim3(8, 16), 256, 0, stream>>>(
      Qryb, Gb, Qk, nullptr, qkb, 2048, 1024, 1024);

  // 5. mega: gates GEMM (1024 x 128x64 tiles) || attention partial (512 blocks)
  mega_k<<<1536, 256, 0, stream>>>(Xcat, Wcat, gates, b_ih, b_hh, Qk, mem, attst);

  // 6. LSTM elementwise + attention finish (h_new row) -> ctx bf16
  lstmfin_k<<<2048, 256, 0, stream>>>(gates, c, Qk, attst, out_h, out_c, ctxb);

  // 7. attended = ctx @ Wv^T + bv
  gemm_bt<<<dim3(8, 16), 256, 0, stream>>>(
      ctxb, Wvb, out_att, nullptr, bv, 2048, 1024, 1024);
}

// Round 7
// 246.784 us; speedup vs baseline: 1.5013x; 1.5013x over previous
//
#include <hip/hip_runtime.h>
#include <stdint.h>

typedef __attribute__((ext_vector_type(8))) short short8;
typedef __attribute__((ext_vector_type(4))) float f32x4;
typedef unsigned short u16;

__device__ __forceinline__ u16 f2bf(float f) {
  union { float f; uint32_t u; } v; v.f = f;
  return (u16)((v.u + 0x7FFFu + ((v.u >> 16) & 1u)) >> 16);
}
__device__ __forceinline__ float bf2f(u16 u) {
  union { uint32_t u; float f; } v; v.u = (uint32_t)u << 16; return v.f;
}

__device__ __forceinline__ void gl_lds16(const void* g, void* l) {
  __builtin_amdgcn_global_load_lds(
      (const __attribute__((address_space(1))) void*)g,
      (__attribute__((address_space(3))) void*)l, 16, 0, 0);
}

// ---------------- generic GEMM (m97 structure, 128x128) ----------------
__global__ __launch_bounds__(256) void gemm_bt(
    const u16* __restrict__ A, const u16* __restrict__ B,
    float* __restrict__ Cf, u16* __restrict__ Cb,
    const float* __restrict__ bias1,
    int M, int N, int K)
{
  __shared__ __align__(16) u16 As[128 * 32];
  __shared__ __align__(16) u16 Bs[128 * 32];
  const int t = threadIdx.x;
  const int lane = t & 63;
  const int w = t >> 6;
  const int wr = w >> 1, wc = w & 1;
  const int m0 = blockIdx.y * 128, n0 = blockIdx.x * 128;
  const int lr = lane & 15;
  const int lk = (lane >> 4) * 8;
  const int srow = t >> 2;
  const int scol = (t & 3) * 8;

  const u16* gA = A + (size_t)(m0 + srow) * K + scol;
  const u16* gB = B + (size_t)(n0 + srow) * K + scol;

  f32x4 acc[4][4] = {};

  for (int k0 = 0; k0 < K; k0 += 32) {
    gl_lds16(gA,                  As + t * 8);
    gl_lds16(gA + (size_t)64 * K, As + 2048 + t * 8);
    gl_lds16(gB,                  Bs + t * 8);
    gl_lds16(gB + (size_t)64 * K, Bs + 2048 + t * 8);
    gA += 32; gB += 32;
    __syncthreads();

    short8 a[4], b[4];
#pragma unroll
    for (int m = 0; m < 4; ++m)
      a[m] = *(const short8*)(As + (wr * 64 + m * 16 + lr) * 32 + lk);
#pragma unroll
    for (int n = 0; n < 4; ++n)
      b[n] = *(const short8*)(Bs + (wc * 64 + n * 16 + lr) * 32 + lk);
#pragma unroll
    for (int m = 0; m < 4; ++m)
#pragma unroll
      for (int n = 0; n < 4; ++n)
        acc[m][n] = __builtin_amdgcn_mfma_f32_16x16x32_bf16(a[m], b[n], acc[m][n], 0, 0, 0);
    __syncthreads();
  }

#pragma unroll
  for (int n = 0; n < 4; ++n) {
    int col = n0 + wc * 64 + n * 16 + lr;
    float bsum = bias1 ? bias1[col] : 0.f;
#pragma unroll
    for (int m = 0; m < 4; ++m) {
#pragma unroll
      for (int r = 0; r < 4; ++r) {
        int row = m0 + wr * 64 + m * 16 + (lane >> 4) * 4 + r;
        float vv = acc[m][n][r] + bsum;
        if (Cf) Cf[(size_t)row * N + col] = vv;
        if (Cb) Cb[(size_t)row * N + col] = f2bf(vv);
      }
    }
  }
}

// ---------------- prep: all f32->bf16 packs + Wq/Wk transposes ----------------
__global__ __launch_bounds__(256) void prep_k(
    const float* __restrict__ pose, const float* __restrict__ h,
    const float* __restrict__ W_ih, const float* __restrict__ W_hh,
    const float* __restrict__ query, const float* __restrict__ Wv,
    const float* __restrict__ Wq, const float* __restrict__ Wk,
    u16* __restrict__ xcat, u16* __restrict__ wcat,
    u16* __restrict__ qry, u16* __restrict__ wvb,
    u16* __restrict__ wqtb, u16* __restrict__ wktb)
{
  __shared__ u16 tile[64][65];
  int blk = blockIdx.x;
  int t = threadIdx.x;
  if (blk >= 15360) {  // transpose-convert: dst[n*1024+a] = bf16(src[a*1024+n])
    const float* src; u16* dst; int tblk;
    if (blk < 15616) { src = Wq; dst = wqtb; tblk = blk - 15360; }
    else             { src = Wk; dst = wktb; tblk = blk - 15616; }
    int tr = (tblk >> 4) * 64, tc = (tblk & 15) * 64;
    int tx = t & 63;
    int ty = (t >> 6) * 16;
#pragma unroll
    for (int i = 0; i < 16; ++i)
      tile[ty + i][tx] = f2bf(src[(size_t)(tr + ty + i) * 1024 + tc + tx]);
    __syncthreads();
#pragma unroll
    for (int i = 0; i < 16; ++i)
      dst[(size_t)(tc + ty + i) * 1024 + tr + tx] = tile[tx][ty + i];
    return;
  }
  const float* src; u16* dst; int ostride, ooff, base;
  if (blk < 2048)       { src = pose;  dst = xcat; ostride = 2048; ooff = 0;    base = 0; }
  else if (blk < 4096)  { src = h;     dst = xcat; ostride = 2048; ooff = 1024; base = 2048; }
  else if (blk < 8192)  { src = W_ih;  dst = wcat; ostride = 2048; ooff = 0;    base = 4096; }
  else if (blk < 12288) { src = W_hh;  dst = wcat; ostride = 2048; ooff = 1024; base = 8192; }
  else if (blk < 14336) { src = query; dst = qry;  ostride = 1024; ooff = 0;    base = 12288; }
  else                  { src = Wv;    dst = wvb;  ostride = 1024; ooff = 0;    base = 14336; }
  int r = blk - base;
  int cc = t * 4;
  float4 v = *(const float4*)(src + (size_t)r * 1024 + cc);
  ushort4 o; o.x = f2bf(v.x); o.y = f2bf(v.y); o.z = f2bf(v.z); o.w = f2bf(v.w);
  *(ushort4*)(dst + (size_t)r * ostride + ooff + cc) = o;
}

// qkb[n] += partial of bq @ Wk (qkb pre-zeroed via memset)
__global__ __launch_bounds__(256) void bqwk_k(
    const float* __restrict__ bq, const float* __restrict__ Wk,
    float* __restrict__ qkb)
{
  int n = blockIdx.x * 256 + threadIdx.x;
  int j0 = blockIdx.y * 64;
  float s = 0.f;
#pragma unroll 8
  for (int j = j0; j < j0 + 64; ++j) s += bq[j] * Wk[(size_t)j * 1024 + n];
  atomicAdd(&qkb[n], s);
}

// ---------------- mega: R3 structure + nt loads on the memory stream --------
// 768 blocks, 3/CU: blk%3 in {0,1} -> gates gemm (512 x 128x128 tiles),
// blk%3==2 -> attn partial (256 blocks, 2 batches/wave sequential).
__global__ __launch_bounds__(256, 3) void mega_k(
    const u16* __restrict__ Xcat, const u16* __restrict__ Wcat,
    u16* __restrict__ gates,
    const float* __restrict__ b_ih, const float* __restrict__ b_hh,
    const float* __restrict__ Qk, const float* __restrict__ mem,
    float* __restrict__ attst)
{
  __shared__ __align__(16) u16 As[128 * 32];
  __shared__ __align__(16) u16 Bs[128 * 32];
  const int blk = blockIdx.x;
  const int t = threadIdx.x;
  const int lane = t & 63;

  if (blk % 3 != 2) {
    // ---- gates GEMM tile 128x128: M=2048 N=4096 K=2048, bf16 out ----
    const int gid = (blk / 3) * 2 + (blk % 3);      // 0..511
    const int m0 = (gid >> 5) * 128, n0 = (gid & 31) * 128;
    const int w = t >> 6;
    const int wr = w >> 1, wc = w & 1;
    const int lr = lane & 15;
    const int lk = (lane >> 4) * 8;
    const int srow = t >> 2;
    const int scol = (t & 3) * 8;

    const u16* gA = Xcat + (size_t)(m0 + srow) * 2048 + scol;
    const u16* gB = Wcat + (size_t)(n0 + srow) * 2048 + scol;

    f32x4 acc[4][4] = {};
    for (int k0 = 0; k0 < 2048; k0 += 32) {
      gl_lds16(gA,                     As + t * 8);
      gl_lds16(gA + (size_t)64 * 2048, As + 2048 + t * 8);
      gl_lds16(gB,                     Bs + t * 8);
      gl_lds16(gB + (size_t)64 * 2048, Bs + 2048 + t * 8);
      gA += 32; gB += 32;
      __syncthreads();
      short8 a[4], b[4];
#pragma unroll
      for (int m = 0; m < 4; ++m)
        a[m] = *(const short8*)(As + (wr * 64 + m * 16 + lr) * 32 + lk);
#pragma unroll
      for (int n = 0; n < 4; ++n)
        b[n] = *(const short8*)(Bs + (wc * 64 + n * 16 + lr) * 32 + lk);
#pragma unroll
      for (int m = 0; m < 4; ++m)
#pragma unroll
        for (int n = 0; n < 4; ++n)
          acc[m][n] = __builtin_amdgcn_mfma_f32_16x16x32_bf16(a[m], b[n], acc[m][n], 0, 0, 0);
      __syncthreads();
    }
#pragma unroll
    for (int n = 0; n < 4; ++n) {
      int col = n0 + wc * 64 + n * 16 + lr;
      float bsum = b_ih[col] + b_hh[col];
#pragma unroll
      for (int m = 0; m < 4; ++m)
#pragma unroll
        for (int r = 0; r < 4; ++r) {
          int row = m0 + wr * 64 + m * 16 + (lane >> 4) * 4 + r;
          gates[(size_t)row * 4096 + col] = f2bf(acc[m][n][r] + bsum);
        }
    }
  } else {
    // ---- attention partial: rows 1..63, 2 batches/wave, nt loads ----
    const int ablk = blk / 3;                        // 0..255
    const int wv_id = t >> 6;
    for (int bi = 0; bi < 2; ++bi) {
      const int b = ablk * 8 + wv_id * 2 + bi;
      const float* q = Qk + (size_t)b * 1024;
      f32x4 qv[4];
#pragma unroll
      for (int i = 0; i < 4; ++i)
        qv[i] = *(const f32x4*)(q + (i * 64 + lane) * 4);
      const float* mb = mem + (size_t)b * 65536;

      float m_run = -3e38f, l = 0.f;
      f32x4 cx[4] = {};

      // 15 quads: rows 1..60
      for (int qd = 0; qd < 15; ++qd) {
        const float* r0 = mb + (size_t)(1 + qd * 4) * 1024;
        f32x4 rv[4][4];
        float s[4] = {0.f, 0.f, 0.f, 0.f};
#pragma unroll
        for (int rr = 0; rr < 4; ++rr)
#pragma unroll
          for (int i = 0; i < 4; ++i) {
            rv[rr][i] = __builtin_nontemporal_load(
                (const f32x4*)(r0 + rr * 1024 + (i * 64 + lane) * 4));
            s[rr] += rv[rr][i][0] * qv[i][0] + rv[rr][i][1] * qv[i][1] +
                     rv[rr][i][2] * qv[i][2] + rv[rr][i][3] * qv[i][3];
          }
#pragma unroll
        for (int rr = 0; rr < 4; ++rr) {
#pragma unroll
          for (int off = 32; off; off >>= 1) s[rr] += __shfl_xor(s[rr], off);
          s[rr] *= 0.03125f;
        }
#pragma unroll
        for (int rr = 0; rr < 4; ++rr) {
          if (s[rr] <= m_run + 8.f) {      // defer-max: common path
            float e = __expf(s[rr] - m_run);
            l += e;
#pragma unroll
            for (int i = 0; i < 4; ++i) cx[i] += rv[rr][i] * e;
          } else {
            float sc = __expf(m_run - s[rr]);
            m_run = s[rr];
            l = l * sc + 1.f;
#pragma unroll
            for (int i = 0; i < 4; ++i) cx[i] = cx[i] * sc + rv[rr][i];
          }
        }
      }
      // rows 61..63 singles
      for (int r = 61; r <= 63; ++r) {
        const float* row = mb + (size_t)r * 1024;
        f32x4 rv[4];
        float s = 0.f;
#pragma unroll
        for (int i = 0; i < 4; ++i) {
          rv[i] = __builtin_nontemporal_load(
              (const f32x4*)(row + (i * 64 + lane) * 4));
          s += rv[i][0] * qv[i][0] + rv[i][1] * qv[i][1] +
               rv[i][2] * qv[i][2] + rv[i][3] * qv[i][3];
        }
#pragma unroll
        for (int off = 32; off; off >>= 1) s += __shfl_xor(s, off);
        s *= 0.03125f;
        if (s <= m_run + 8.f) {
          float e = __expf(s - m_run);
          l += e;
#pragma unroll
          for (int i = 0; i < 4; ++i) cx[i] += rv[i] * e;
        } else {
          float sc = __expf(m_run - s);
          m_run = s;
          l = l * sc + 1.f;
#pragma unroll
          for (int i = 0; i < 4; ++i) cx[i] = cx[i] * sc + rv[i];
        }
      }
      // store state
      float* st = attst + (size_t)b * 1032;
#pragma unroll
      for (int i = 0; i < 4; ++i)
        *(f32x4*)(st + (i * 64 + lane) * 4) = cx[i];
      if (lane == 0) { st[1024] = m_run; st[1025] = l; }
    }
  }
}

// ---------------- fused LSTM elementwise + attention finish ----------------
__global__ __launch_bounds__(256) void lstmfin_k(
    const u16* __restrict__ gates, const float* __restrict__ c,
    const float* __restrict__ Qk, const float* __restrict__ attst,
    float* __restrict__ out_h, float* __restrict__ out_c,
    u16* __restrict__ ctxb)
{
  const int b = blockIdx.x;
  const int t = threadIdx.x;
  const int lane = t & 63, wv_id = t >> 6;
  const int p = t * 4;
  const u16* g = gates + (size_t)b * 4096;
  ushort4 igu = *(const ushort4*)(g + p);
  ushort4 fgu = *(const ushort4*)(g + 1024 + p);
  ushort4 ggu = *(const ushort4*)(g + 2048 + p);
  ushort4 ogu = *(const ushort4*)(g + 3072 + p);
  float4 cv = *(const float4*)(c + (size_t)b * 1024 + p);

  float hn[4], cn[4];
  {
    float igs[4] = {bf2f(igu.x), bf2f(igu.y), bf2f(igu.z), bf2f(igu.w)};
    float fgs[4] = {bf2f(fgu.x), bf2f(fgu.y), bf2f(fgu.z), bf2f(fgu.w)};
    float ggs[4] = {bf2f(ggu.x), bf2f(ggu.y), bf2f(ggu.z), bf2f(ggu.w)};
    float ogs[4] = {bf2f(ogu.x), bf2f(ogu.y), bf2f(ogu.z), bf2f(ogu.w)};
    float cvs[4] = {cv.x, cv.y, cv.z, cv.w};
#pragma unroll
    for (int j = 0; j < 4; ++j) {
      float si = 1.f / (1.f + __expf(-igs[j]));
      float sf = 1.f / (1.f + __expf(-fgs[j]));
      float so = 1.f / (1.f + __expf(-ogs[j]));
      float tg = 2.f / (1.f + __expf(-2.f * ggs[j])) - 1.f;
      cn[j] = sf * cvs[j] + si * tg;
      float tc2 = 2.f / (1.f + __expf(-2.f * cn[j])) - 1.f;
      hn[j] = so * tc2;
    }
  }
  *(float4*)(out_c + (size_t)b * 1024 + p) = make_float4(cn[0], cn[1], cn[2], cn[3]);
  *(float4*)(out_h + (size_t)b * 1024 + p) = make_float4(hn[0], hn[1], hn[2], hn[3]);

  // s_last = dot(Qk[b], h_new[b]) / 32  (block reduction)
  float4 qv = *(const float4*)(Qk + (size_t)b * 1024 + p);
  float part = qv.x * hn[0] + qv.y * hn[1] + qv.z * hn[2] + qv.w * hn[3];
#pragma unroll
  for (int off = 32; off; off >>= 1) part += __shfl_xor(part, off);
  __shared__ float red[4];
  if (lane == 0) red[wv_id] = part;
  __syncthreads();
  float s_last = (red[0] + red[1] + red[2] + red[3]) * 0.03125f;

  const float* st = attst + (size_t)b * 1032;
  float m_run = st[1024], l = st[1025];
  float4 cx = *(const float4*)(st + p);
  if (s_last <= m_run + 8.f) {
    float e = __expf(s_last - m_run);
    l += e;
    cx.x += e * hn[0]; cx.y += e * hn[1]; cx.z += e * hn[2]; cx.w += e * hn[3];
  } else {
    float sc = __expf(m_run - s_last);
    l = l * sc + 1.f;
    cx.x = cx.x * sc + hn[0]; cx.y = cx.y * sc + hn[1];
    cx.z = cx.z * sc + hn[2]; cx.w = cx.w * sc + hn[3];
  }
  float inv = 1.f / l;
  ushort4 o;
  o.x = f2bf(cx.x * inv); o.y = f2bf(cx.y * inv);
  o.z = f2bf(cx.z * inv); o.w = f2bf(cx.w * inv);
  *(ushort4*)(ctxb + (size_t)b * 1024 + p) = o;
}

extern "C" void kernel_launch(void* const* d_in, const int* in_sizes, int n_in,
                              void* d_out, int out_size, void* d_ws, size_t ws_size,
                              hipStream_t stream) {
  const int Bb = 2048, Hh = 1024;
  const float* pose  = (const float*)d_in[0];
  const float* query = (const float*)d_in[1];
  const float* h     = (const float*)d_in[2];
  const float* c     = (const float*)d_in[3];
  const float* mem   = (const float*)d_in[4];
  const float* W_ih  = (const float*)d_in[5];
  const float* W_hh  = (const float*)d_in[6];
  const float* b_ih  = (const float*)d_in[7];
  const float* b_hh  = (const float*)d_in[8];
  const float* Wq    = (const float*)d_in[9];
  const float* bq    = (const float*)d_in[10];
  const float* Wk    = (const float*)d_in[11];
  // d_in[12] = bk: m-independent score shift, cancels in softmax
  const float* Wv    = (const float*)d_in[13];
  const float* bv    = (const float*)d_in[14];

  float* out_att = (float*)d_out;
  float* out_h   = out_att + (size_t)Bb * Hh;
  float* out_c   = out_h + (size_t)Bb * Hh;

  char* wp = (char*)d_ws;
  auto alloc = [&](size_t bytes) {
    char* p = wp; wp += (bytes + 255) & ~(size_t)255; return p;
  };
  u16*   Xcat  = (u16*)alloc((size_t)2048 * 2048 * 2);   // 8 MB
  u16*   Wcat  = (u16*)alloc((size_t)4096 * 2048 * 2);   // 16 MB
  // next 4 contiguous, all dead before mega -> attst aliases them
  u16*   Qryb  = (u16*)alloc((size_t)2048 * 1024 * 2);   // 4 MB
  u16*   WqTb  = (u16*)alloc((size_t)1024 * 1024 * 2);   // 2 MB
  u16*   WkTb  = (u16*)alloc((size_t)1024 * 1024 * 2);   // 2 MB
  u16*   Gb    = (u16*)alloc((size_t)1024 * 1024 * 2);   // 2 MB
  u16*   Wvb   = (u16*)alloc((size_t)1024 * 1024 * 2);   // 2 MB (live through final)
  u16*   gates = (u16*)alloc((size_t)2048 * 4096 * 2);   // 16 MB (bf16)
  float* qkb   = (float*)alloc((size_t)1024 * 4);
  float* Qk    = (float*)alloc((size_t)2048 * 1024 * 4); // 8 MB
  u16*   ctxb  = (u16*)alloc((size_t)2048 * 1024 * 2);   // 4 MB
  float* attst = (float*)Qryb;   // [2048][1032] f32 = 8.45 MB < 10 MB alias pool

  // 1. all conversions in one kernel
  prep_k<<<15872, 256, 0, stream>>>(pose, h, W_ih, W_hh, query, Wv, Wq, Wk,
                                    Xcat, Wcat, Qryb, Wvb, WqTb, WkTb);

  // 2. qkb = bq @ Wk (tiny)
  hipMemsetAsync(qkb, 0, 1024 * sizeof(float), stream);
  bqwk_k<<<dim3(4, 16), 256, 0, stream>>>(bq, Wk, qkb);

  // 3. G[n,j] = sum_a Wk[a,n]*Wq[a,j]  (query @ G^T == (query@Wq^T)@Wk)
  gemm_bt<<<dim3(8, 8), 256, 0, stream>>>(
      WkTb, WqTb, nullptr, Gb, nullptr, 1024, 1024, 1024);

  // 4. Qk = query @ G^T + bq@Wk
  gemm_bt<<<dim3(8, 16), 256, 0, stream>>>(
      Qryb, Gb, Qk, nullptr, qkb, 2048, 1024, 1024);

  // 5. mega: gates GEMM (512 x 128x128 tiles) || attn partial (256 blocks, nt)
  mega_k<<<768, 256, 0, stream>>>(Xcat, Wcat, gates, b_ih, b_hh, Qk, mem, attst);

  // 6. LSTM elementwise + attention finish (h_new row) -> ctx bf16
  lstmfin_k<<<2048, 256, 0, stream>>>(gates, c, Qk, attst, out_h, out_c, ctxb);

  // 7. attended = ctx @ Wv^T + bv
  gemm_bt<<<dim3(8, 16), 256, 0, stream>>>(
      ctxb, Wvb, out_att, nullptr, bv, 2048, 1024, 1024);
}